// Round 1
// baseline (1378.881 us; speedup 1.0000x reference)
//
#include <hip/hip_runtime.h>

// SimpleODELSTM: B=4096, T=512, H=64, INPUT=2, NCLS=64.
// Persistent-block design: 256 blocks x 16 batch rows, 4 waves/block.
// Wave w owns output cols [16w, 16w+16) of every matmul (gates ntiles {w, w+4, w+8, w+12}).
// Weights live in registers as fp16 MFMA B-fragments; h/u transposed via 6KB LDS per step.
// State (h, c) kept fp32 in registers (D-fragment layout); matmul I/O rounded to fp16.

#define TT 512
#define DT 0.33333334f

typedef _Float16 half8 __attribute__((ext_vector_type(8)));
typedef float f32x4 __attribute__((ext_vector_type(4)));

__device__ __forceinline__ float fsig(float x) {
  return __builtin_amdgcn_rcpf(1.0f + __expf(-x));
}
__device__ __forceinline__ float ftanh(float x) {
  return 2.0f * __builtin_amdgcn_rcpf(1.0f + __expf(-2.0f * x)) - 1.0f;
}

// A-plane: [16 rows][64 cols] fp16, row-major, 8-col chunks XOR-swizzled by (row&7).
// A-fragment for mfma_f32_16x16x32_f16: lane l supplies A[l&15][ (l>>4)*8 + i ] (+32 for kt=1).
__device__ __forceinline__ half8 rdA(const _Float16* plane, int p, int kt, int q) {
  return *(const half8*)(plane + p * 64 + ((((kt << 2) | q) ^ (p & 7)) << 3));
}

__global__ void __launch_bounds__(256, 1)
odelstm(const float* __restrict__ X, const float* __restrict__ Wih,
        const float* __restrict__ Whh, const float* __restrict__ bih,
        const float* __restrict__ bhh, const float* __restrict__ W1,
        const float* __restrict__ b1, const float* __restrict__ W2,
        const float* __restrict__ b2, const float* __restrict__ Wf,
        const float* __restrict__ bf, float* __restrict__ OUT)
{
  __shared__ __align__(16) _Float16 hA[2][1024];  // ping-pong h A-planes
  __shared__ __align__(16) _Float16 uA[1024];     // u A-plane

  const int tid = (int)threadIdx.x;
  const int w = tid >> 6;        // wave id 0..3 -> owns cols [16w,16w+16)
  const int l = tid & 63;
  const int q = l >> 4;          // lane quad 0..3
  const int p = l & 15;          // lane-in-quad
  const int j = (w << 4) | p;    // owned hidden/class column
  const int row0 = (int)blockIdx.x << 4;

  // ---- preload weight B-fragments (fp16) into registers ----
  // B-fragment: lane l supplies B[k = kt*32 + (l>>4)*8 + i][n = ncol]; B[k][n] = W[n][k].
  half8 Bhh[4][2], Bo1[2], Bo2[2], Bof[2];
  #pragma unroll
  for (int g = 0; g < 4; ++g) {
    #pragma unroll
    for (int kt = 0; kt < 2; ++kt) {
      const float* s = Whh + ((g << 6) | j) * 64 + (kt << 5) + (q << 3);
      half8 v;
      #pragma unroll
      for (int i = 0; i < 8; ++i) v[i] = (_Float16)s[i];
      Bhh[g][kt] = v;
    }
  }
  #pragma unroll
  for (int kt = 0; kt < 2; ++kt) {
    const float* s1 = W1 + j * 64 + (kt << 5) + (q << 3);
    const float* s2 = W2 + j * 64 + (kt << 5) + (q << 3);
    const float* sf = Wf + j * 64 + (kt << 5) + (q << 3);
    half8 v1, v2, vf;
    #pragma unroll
    for (int i = 0; i < 8; ++i) {
      v1[i] = (_Float16)s1[i]; v2[i] = (_Float16)s2[i]; vf[i] = (_Float16)sf[i];
    }
    Bo1[kt] = v1; Bo2[kt] = v2; Bof[kt] = vf;
  }

  // per-lane step-invariant constants
  float bias4[4], wx0[4], wx1[4];
  #pragma unroll
  for (int g = 0; g < 4; ++g) {
    int gr = (g << 6) | j;
    bias4[g] = bih[gr] + bhh[gr];
    wx0[g] = Wih[gr * 2];
    wx1[g] = Wih[gr * 2 + 1];
  }
  const float b1c = b1[j], b2c = b2[j], bfc = bf[j];

  // zero initial h plane (h0 = 0)
  for (int i = tid; i < 1024; i += 256) hA[0][i] = (_Float16)0.f;

  float c[4]  = {0.f, 0.f, 0.f, 0.f};
  float hd[4] = {0.f, 0.f, 0.f, 0.f};  // h in D-fragment layout (fp32)

  int rb[4];
  #pragma unroll
  for (int r = 0; r < 4; ++r) rb[r] = row0 + ((q << 2) | r);

  // x prefetch for t=0: x[b][ch][t] flat = (b*2+ch)*T + t
  float x0[4], x1[4];
  #pragma unroll
  for (int r = 0; r < 4; ++r) {
    x0[r] = X[(rb[r] * 2) * TT];
    x1[r] = X[(rb[r] * 2 + 1) * TT];
  }

  __syncthreads();

  int hcur = 0;
  for (int t = 0; t < TT; ++t) {
    // prefetch next step's x early (latency hidden under this step's compute)
    int tn = (t + 1 < TT) ? t + 1 : t;
    float nx0[4], nx1[4];
    #pragma unroll
    for (int r = 0; r < 4; ++r) {
      nx0[r] = X[(rb[r] * 2) * TT + tn];
      nx1[r] = X[(rb[r] * 2 + 1) * TT + tn];
    }

    // ---- gates = x@Wih^T + bias (VALU) + h@Whh^T (MFMA) ----
    f32x4 acc[4];
    #pragma unroll
    for (int g = 0; g < 4; ++g) {
      #pragma unroll
      for (int r = 0; r < 4; ++r)
        acc[g][r] = bias4[g] + x0[r] * wx0[g] + x1[r] * wx1[g];
    }
    {
      half8 a0 = rdA(hA[hcur], p, 0, q);
      half8 a1 = rdA(hA[hcur], p, 1, q);
      #pragma unroll
      for (int g = 0; g < 4; ++g) {
        acc[g] = __builtin_amdgcn_mfma_f32_16x16x32_f16(a0, Bhh[g][0], acc[g], 0, 0, 0);
        acc[g] = __builtin_amdgcn_mfma_f32_16x16x32_f16(a1, Bhh[g][1], acc[g], 0, 0, 0);
      }
    }

    // ---- LSTM pointwise (all lane-local: i,f,g,o share (row, j)) ----
    #pragma unroll
    for (int r = 0; r < 4; ++r) {
      float ig = fsig(acc[0][r]);
      float fg = fsig(acc[1][r]);
      float gg = ftanh(acc[2][r]);
      float og = fsig(acc[3][r]);
      c[r]  = fg * c[r] + ig * gg;
      hd[r] = og * ftanh(c[r]);
    }

    // ---- 3 fixed-Euler ODE iterations ----
    #pragma unroll
    for (int it = 0; it < 3; ++it) {
      {  // transpose h (D-frags) -> A-plane (fp16, swizzled)
        _Float16* pl = hA[hcur ^ 1];
        #pragma unroll
        for (int r = 0; r < 4; ++r) {
          int row = (q << 2) | r;
          pl[row * 64 + (((j >> 3) ^ (row & 7)) << 3) + (j & 7)] = (_Float16)hd[r];
        }
      }
      __syncthreads();
      hcur ^= 1;
      half8 ah0 = rdA(hA[hcur], p, 0, q);
      half8 ah1 = rdA(hA[hcur], p, 1, q);
      f32x4 ua = {0.f, 0.f, 0.f, 0.f};
      ua = __builtin_amdgcn_mfma_f32_16x16x32_f16(ah0, Bo1[0], ua, 0, 0, 0);
      ua = __builtin_amdgcn_mfma_f32_16x16x32_f16(ah1, Bo1[1], ua, 0, 0, 0);
      float u[4];
      #pragma unroll
      for (int r = 0; r < 4; ++r) u[r] = ftanh(ua[r] + b1c);
      {
        #pragma unroll
        for (int r = 0; r < 4; ++r) {
          int row = (q << 2) | r;
          uA[row * 64 + (((j >> 3) ^ (row & 7)) << 3) + (j & 7)] = (_Float16)u[r];
        }
      }
      __syncthreads();
      half8 au0 = rdA(uA, p, 0, q);
      half8 au1 = rdA(uA, p, 1, q);
      f32x4 da = {0.f, 0.f, 0.f, 0.f};
      da = __builtin_amdgcn_mfma_f32_16x16x32_f16(au0, Bo2[0], da, 0, 0, 0);
      da = __builtin_amdgcn_mfma_f32_16x16x32_f16(au1, Bo2[1], da, 0, 0, 0);
      #pragma unroll
      for (int r = 0; r < 4; ++r) hd[r] += DT * (da[r] + b2c);
    }

    // ---- final h plane (feeds out-proj now and gates at t+1) ----
    {
      _Float16* pl = hA[hcur ^ 1];
      #pragma unroll
      for (int r = 0; r < 4; ++r) {
        int row = (q << 2) | r;
        pl[row * 64 + (((j >> 3) ^ (row & 7)) << 3) + (j & 7)] = (_Float16)hd[r];
      }
    }
    __syncthreads();
    hcur ^= 1;

    // ---- out = h@Wf^T + bf ----
    {
      half8 hf0 = rdA(hA[hcur], p, 0, q);
      half8 hf1 = rdA(hA[hcur], p, 1, q);
      f32x4 oa = {0.f, 0.f, 0.f, 0.f};
      oa = __builtin_amdgcn_mfma_f32_16x16x32_f16(hf0, Bof[0], oa, 0, 0, 0);
      oa = __builtin_amdgcn_mfma_f32_16x16x32_f16(hf1, Bof[1], oa, 0, 0, 0);
      #pragma unroll
      for (int r = 0; r < 4; ++r)
        OUT[(rb[r] * TT + t) * 64 + j] = oa[r] + bfc;
    }

    #pragma unroll
    for (int r = 0; r < 4; ++r) { x0[r] = nx0[r]; x1[r] = nx1[r]; }
  }
}

extern "C" void kernel_launch(void* const* d_in, const int* in_sizes, int n_in,
                              void* d_out, int out_size, void* d_ws, size_t ws_size,
                              hipStream_t stream) {
  const float* X   = (const float*)d_in[0];
  const float* Wih = (const float*)d_in[1];
  const float* Whh = (const float*)d_in[2];
  const float* bih = (const float*)d_in[3];
  const float* bhh = (const float*)d_in[4];
  const float* W1  = (const float*)d_in[5];
  const float* b1  = (const float*)d_in[6];
  const float* W2  = (const float*)d_in[7];
  const float* b2  = (const float*)d_in[8];
  const float* Wf  = (const float*)d_in[9];
  const float* bf  = (const float*)d_in[10];
  float* OUT = (float*)d_out;

  int B = in_sizes[0] / (2 * TT);   // 4096
  dim3 grid(B / 16), block(256);
  hipLaunchKernelGGL(odelstm, grid, block, 0, stream,
                     X, Wih, Whh, bih, bhh, W1, b1, W2, b2, Wf, bf, OUT);
}

// Round 4
// 1190.068 us; speedup vs baseline: 1.1587x; 1.1587x over previous
//
#include <hip/hip_runtime.h>

// SimpleODELSTM: B=4096, T=512, H=64, INPUT=2, NCLS=64.
// R1 (resubmitted unchanged after broker timeouts x2): algebraic transpose
// elimination. With a_i = W1 h_i + b1, t_i = tanh(a_i):
//   a_{i+1} = a_i + [dt W1W2] t_i + dt W1 b2
//   h3 = h_new + dt W2 (t0+t1+t2) + 3dt b2  (never materialized)
//   Whh h3 = Whh h_new + [dt WhhW2] S + 3dt Whh b2   (gates for t+1)
//   Wf  h3 = Wf  h_new + [dt WfW2 ] S + (3dt Wf b2 + bf)   (out_t)
// => 4 LDS transposes + 4 barriers per step (was 7+7).
// Prep kernel computes folded matrices M',N',P' and bias folds into d_ws.

#define TT 512
#define DT 0.33333334f

// ws layout (floats)
#define OFF_M  0        // dt*W1@W2      [64][64]
#define OFF_N  4096     // dt*Whh@W2     [256][64]
#define OFF_P  20480    // dt*Wf@W2      [64][64]
#define OFF_K1 24576    // dt*W1@b2      [64]
#define OFF_CG 24640    // 3dt*Whh@b2    [256]
#define OFF_C2 24896    // 3dt*Wf@b2+bf  [64]

typedef _Float16 half8 __attribute__((ext_vector_type(8)));
typedef float f32x4 __attribute__((ext_vector_type(4)));

__device__ __forceinline__ float fsig(float x) {
  return __builtin_amdgcn_rcpf(1.0f + __expf(-x));
}
__device__ __forceinline__ float ftanh(float x) {
  return 2.0f * __builtin_amdgcn_rcpf(1.0f + __expf(-2.0f * x)) - 1.0f;
}

__global__ void prep(const float* __restrict__ Whh, const float* __restrict__ W1,
                     const float* __restrict__ W2, const float* __restrict__ b2,
                     const float* __restrict__ Wf, const float* __restrict__ bf,
                     float* __restrict__ ws) {
  int id = (int)blockIdx.x * 256 + (int)threadIdx.x;
  if (id < 4096) {                       // M' = dt * W1 @ W2
    int j = id >> 6, k = id & 63;
    float s = 0.f;
    for (int l = 0; l < 64; ++l) s += W1[j * 64 + l] * W2[l * 64 + k];
    ws[OFF_M + id] = DT * s;
  } else if (id < 20480) {               // N' = dt * Whh @ W2
    int e = id - 4096; int gr = e >> 6, k = e & 63;
    float s = 0.f;
    for (int l = 0; l < 64; ++l) s += Whh[gr * 64 + l] * W2[l * 64 + k];
    ws[OFF_N + e] = DT * s;
  } else if (id < 24576) {               // P' = dt * Wf @ W2
    int e = id - 20480; int j = e >> 6, k = e & 63;
    float s = 0.f;
    for (int l = 0; l < 64; ++l) s += Wf[j * 64 + l] * W2[l * 64 + k];
    ws[OFF_P + e] = DT * s;
  } else if (id < 24640) {               // k1 = dt * W1 @ b2
    int j = id - 24576;
    float s = 0.f;
    for (int l = 0; l < 64; ++l) s += W1[j * 64 + l] * b2[l];
    ws[OFF_K1 + j] = DT * s;
  } else if (id < 24896) {               // cg = 3dt * Whh @ b2
    int gr = id - 24640;
    float s = 0.f;
    for (int l = 0; l < 64; ++l) s += Whh[gr * 64 + l] * b2[l];
    ws[OFF_CG + gr] = 3.0f * DT * s;
  } else if (id < 24960) {               // c2 = 3dt * Wf @ b2 + bf
    int j = id - 24896;
    float s = 0.f;
    for (int l = 0; l < 64; ++l) s += Wf[j * 64 + l] * b2[l];
    ws[OFF_C2 + j] = 3.0f * DT * s + bf[j];
  }
}

// A-plane: [16 rows][64 cols] fp16, 8-col chunks XOR-swizzled by (row&7).
__device__ __forceinline__ half8 rdA(const _Float16* plane, int off) {
  return *(const half8*)(plane + off);
}

__global__ void __launch_bounds__(256, 1)
odelstm(const float* __restrict__ X, const float* __restrict__ Wih,
        const float* __restrict__ Whh, const float* __restrict__ bih,
        const float* __restrict__ bhh, const float* __restrict__ W1,
        const float* __restrict__ b1, const float* __restrict__ Wf,
        const float* __restrict__ ws, float* __restrict__ OUT)
{
  // planes (1024 halfs each): H0, H1 (ping-pong h_new), T0, T1, Sp
  __shared__ __align__(16) _Float16 sh[5 * 1024];

  const int tid = (int)threadIdx.x;
  const int w = tid >> 6;
  const int l = tid & 63;
  const int q = l >> 4;
  const int p = l & 15;
  const int j = (w << 4) | p;        // owned output column
  const int row0 = (int)blockIdx.x << 4;

  // ---- weight B-fragments (fp16) in registers ----
  // lane supplies B[k = kt*32 + q*8 + i][n = j]  = Mat[j][k]
  half8 Bhh[4][2], Bw1[2], Bm[2], Bn[4][2], Bp[2], Bof[2];
  #pragma unroll
  for (int g = 0; g < 4; ++g) {
    #pragma unroll
    for (int kt = 0; kt < 2; ++kt) {
      const float* s  = Whh + ((g << 6) | j) * 64 + (kt << 5) + (q << 3);
      const float* sn = ws + OFF_N + (((g << 6) | j) << 6) + (kt << 5) + (q << 3);
      half8 v, vn;
      #pragma unroll
      for (int i = 0; i < 8; ++i) { v[i] = (_Float16)s[i]; vn[i] = (_Float16)sn[i]; }
      Bhh[g][kt] = v; Bn[g][kt] = vn;
    }
  }
  #pragma unroll
  for (int kt = 0; kt < 2; ++kt) {
    const float* s1 = W1 + j * 64 + (kt << 5) + (q << 3);
    const float* sm = ws + OFF_M + (j << 6) + (kt << 5) + (q << 3);
    const float* sp = ws + OFF_P + (j << 6) + (kt << 5) + (q << 3);
    const float* sf = Wf + j * 64 + (kt << 5) + (q << 3);
    half8 v1, vm, vp, vf;
    #pragma unroll
    for (int i = 0; i < 8; ++i) {
      v1[i] = (_Float16)s1[i]; vm[i] = (_Float16)sm[i];
      vp[i] = (_Float16)sp[i]; vf[i] = (_Float16)sf[i];
    }
    Bw1[kt] = v1; Bm[kt] = vm; Bp[kt] = vp; Bof[kt] = vf;
  }

  // per-lane constants
  float bias0[4], biasL[4], wx0[4], wx1[4];
  #pragma unroll
  for (int g = 0; g < 4; ++g) {
    int gr = (g << 6) | j;
    bias0[g] = bih[gr] + bhh[gr];
    biasL[g] = bias0[g] + ws[OFF_CG + gr];
    wx0[g] = Wih[gr * 2];
    wx1[g] = Wih[gr * 2 + 1];
  }
  const float b1c = b1[j];
  const float k1c = ws[OFF_K1 + j];
  const float c2c = ws[OFF_C2 + j];

  // loop-invariant LDS addresses
  int waddr[4];
  #pragma unroll
  for (int r = 0; r < 4; ++r) {
    int row = (q << 2) | r;
    waddr[r] = row * 64 + (((j >> 3) ^ (row & 7)) << 3) + (j & 7);
  }
  int roff0 = p * 64 + (((q) ^ (p & 7)) << 3);
  int roff1 = p * 64 + (((4 | q) ^ (p & 7)) << 3);

  // global pointers
  const float* xp[4];
  float* outp[4];
  #pragma unroll
  for (int r = 0; r < 4; ++r) {
    int rb = row0 + ((q << 2) | r);
    xp[r]   = X + rb * 2 * TT;               // ch0 at [t], ch1 at [TT + t]
    outp[r] = OUT + (rb * TT) * 64 + j;
  }

  // prologue: x(0), gates(0) = x Wih + bias (h0 = 0)
  float x0[4], x1[4];
  #pragma unroll
  for (int r = 0; r < 4; ++r) { x0[r] = xp[r][0]; x1[r] = xp[r][TT]; }

  f32x4 acc[4];
  #pragma unroll
  for (int g = 0; g < 4; ++g)
    #pragma unroll
    for (int r = 0; r < 4; ++r)
      acc[g][r] = bias0[g] + x0[r] * wx0[g] + x1[r] * wx1[g];

  float c[4] = {0.f, 0.f, 0.f, 0.f};

  for (int t = 0; t < TT; ++t) {
    _Float16* Hpl = sh + ((t & 1) << 10);       // H0 / H1
    _Float16* T0p = sh + 2048;
    _Float16* T1p = sh + 3072;
    _Float16* Spp = sh + 4096;

    // ---- phase 1: LSTM pointwise -> h_new; write H plane ----
    float hd[4];
    #pragma unroll
    for (int r = 0; r < 4; ++r) {
      float ig = fsig(acc[0][r]);
      float fg = fsig(acc[1][r]);
      float gg = ftanh(acc[2][r]);
      float og = fsig(acc[3][r]);
      c[r]  = fg * c[r] + ig * gg;
      hd[r] = og * ftanh(c[r]);
      Hpl[waddr[r]] = (_Float16)hd[r];
    }
    __syncthreads();  // b1

    // ---- phase 2: a0 = W1 h_new + b1 ; prefetch x(t+1) ----
    half8 hf0 = rdA(Hpl, roff0);
    half8 hf1 = rdA(Hpl, roff1);
    f32x4 aa = {b1c, b1c, b1c, b1c};
    aa = __builtin_amdgcn_mfma_f32_16x16x32_f16(hf0, Bw1[0], aa, 0, 0, 0);
    aa = __builtin_amdgcn_mfma_f32_16x16x32_f16(hf1, Bw1[1], aa, 0, 0, 0);

    int tn = (t + 1 < TT) ? t + 1 : t;
    float nx0[4], nx1[4];
    #pragma unroll
    for (int r = 0; r < 4; ++r) { nx0[r] = xp[r][tn]; nx1[r] = xp[r][TT + tn]; }

    // ---- phase 3: t0 = tanh(a0); a1 = a0 + M' t0 + k1 ----
    float t0s[4];
    #pragma unroll
    for (int r = 0; r < 4; ++r) {
      t0s[r] = ftanh(aa[r]);
      T0p[waddr[r]] = (_Float16)t0s[r];
    }
    __syncthreads();  // b2
    half8 t0f0 = rdA(T0p, roff0);
    half8 t0f1 = rdA(T0p, roff1);
    f32x4 a1 = {aa[0] + k1c, aa[1] + k1c, aa[2] + k1c, aa[3] + k1c};
    a1 = __builtin_amdgcn_mfma_f32_16x16x32_f16(t0f0, Bm[0], a1, 0, 0, 0);
    a1 = __builtin_amdgcn_mfma_f32_16x16x32_f16(t0f1, Bm[1], a1, 0, 0, 0);

    // ---- phase 4: t1 = tanh(a1); a2 = a1 + M' t1 + k1 ----
    float t1s[4];
    #pragma unroll
    for (int r = 0; r < 4; ++r) {
      t1s[r] = ftanh(a1[r]);
      T1p[waddr[r]] = (_Float16)t1s[r];
    }
    __syncthreads();  // b3
    half8 t1f0 = rdA(T1p, roff0);
    half8 t1f1 = rdA(T1p, roff1);
    f32x4 a2 = {a1[0] + k1c, a1[1] + k1c, a1[2] + k1c, a1[3] + k1c};
    a2 = __builtin_amdgcn_mfma_f32_16x16x32_f16(t1f0, Bm[0], a2, 0, 0, 0);
    a2 = __builtin_amdgcn_mfma_f32_16x16x32_f16(t1f1, Bm[1], a2, 0, 0, 0);

    // ---- phase 5: t2 = tanh(a2); S = t0+t1+t2; write Sp ----
    #pragma unroll
    for (int r = 0; r < 4; ++r) {
      float Sv = t0s[r] + t1s[r] + ftanh(a2[r]);
      Spp[waddr[r]] = (_Float16)Sv;
    }
    __syncthreads();  // b4

    // ---- phase 6: gates(t+1) = x Wih + biasL + Whh H + N' S ;
    //               out_t = Wf H + P' S + c2 ----
    half8 sf0 = rdA(Spp, roff0);
    half8 sf1 = rdA(Spp, roff1);

    #pragma unroll
    for (int g = 0; g < 4; ++g) {
      #pragma unroll
      for (int r = 0; r < 4; ++r)
        acc[g][r] = biasL[g] + nx0[r] * wx0[g] + nx1[r] * wx1[g];
      acc[g] = __builtin_amdgcn_mfma_f32_16x16x32_f16(hf0, Bhh[g][0], acc[g], 0, 0, 0);
      acc[g] = __builtin_amdgcn_mfma_f32_16x16x32_f16(hf1, Bhh[g][1], acc[g], 0, 0, 0);
      acc[g] = __builtin_amdgcn_mfma_f32_16x16x32_f16(sf0, Bn[g][0],  acc[g], 0, 0, 0);
      acc[g] = __builtin_amdgcn_mfma_f32_16x16x32_f16(sf1, Bn[g][1],  acc[g], 0, 0, 0);
    }

    f32x4 oa = {c2c, c2c, c2c, c2c};
    oa = __builtin_amdgcn_mfma_f32_16x16x32_f16(hf0, Bof[0], oa, 0, 0, 0);
    oa = __builtin_amdgcn_mfma_f32_16x16x32_f16(hf1, Bof[1], oa, 0, 0, 0);
    oa = __builtin_amdgcn_mfma_f32_16x16x32_f16(sf0, Bp[0],  oa, 0, 0, 0);
    oa = __builtin_amdgcn_mfma_f32_16x16x32_f16(sf1, Bp[1],  oa, 0, 0, 0);

    #pragma unroll
    for (int r = 0; r < 4; ++r) {
      outp[r][0] = oa[r];
      outp[r] += 64;
    }

    #pragma unroll
    for (int r = 0; r < 4; ++r) { x0[r] = nx0[r]; x1[r] = nx1[r]; }
  }
}

extern "C" void kernel_launch(void* const* d_in, const int* in_sizes, int n_in,
                              void* d_out, int out_size, void* d_ws, size_t ws_size,
                              hipStream_t stream) {
  const float* X   = (const float*)d_in[0];
  const float* Wih = (const float*)d_in[1];
  const float* Whh = (const float*)d_in[2];
  const float* bih = (const float*)d_in[3];
  const float* bhh = (const float*)d_in[4];
  const float* W1  = (const float*)d_in[5];
  const float* b1  = (const float*)d_in[6];
  const float* W2  = (const float*)d_in[7];
  const float* b2  = (const float*)d_in[8];
  const float* Wf  = (const float*)d_in[9];
  const float* bf  = (const float*)d_in[10];
  float* OUT = (float*)d_out;
  float* ws  = (float*)d_ws;

  hipLaunchKernelGGL(prep, dim3(98), dim3(256), 0, stream,
                     Whh, W1, W2, b2, Wf, bf, ws);

  int B = in_sizes[0] / (2 * TT);   // 4096
  dim3 grid(B / 16), block(256);
  hipLaunchKernelGGL(odelstm, grid, block, 0, stream,
                     X, Wih, Whh, bih, bhh, W1, b1, Wf, ws, OUT);
}

// Round 9
// 1075.892 us; speedup vs baseline: 1.2816x; 1.1061x over previous
//
#include <hip/hip_runtime.h>

// SimpleODELSTM: B=4096, T=512, H=64, INPUT=2, NCLS=64.
// R4 (resubmitted unchanged; infra failures x4 on this exact source):
// occupancy packing. 512 blocks x 8 batch rows -> 2 blocks/CU (2 waves/SIMD),
// so one block's barrier/LDS-latency stalls hide under the other block's issue.
// Batch rows sit in MFMA tile rows {q*4+0, q*4+1} (2 valid rows per lane quad),
// halving per-lane pointwise/transcendental work; dead tile rows stay zero.
// Keeps R1's algebraic transpose elimination (4 LDS planes + 4 barriers/step):
//   a_{i+1} = a_i + [dt W1W2] t_i + dt W1 b2
//   Whh h3  = Whh h_new + [dt WhhW2] S + 3dt Whh b2   (gates t+1)
//   Wf  h3  = Wf  h_new + [dt WfW2 ] S + (3dt Wf b2 + bf)   (out_t)

#define TT 512
#define DT 0.33333334f

// ws layout (floats)
#define OFF_M  0        // dt*W1@W2      [64][64]
#define OFF_N  4096     // dt*Whh@W2     [256][64]
#define OFF_P  20480    // dt*Wf@W2      [64][64]
#define OFF_K1 24576    // dt*W1@b2      [64]
#define OFF_CG 24640    // 3dt*Whh@b2    [256]
#define OFF_C2 24896    // 3dt*Wf@b2+bf  [64]

typedef _Float16 half8 __attribute__((ext_vector_type(8)));
typedef float f32x4 __attribute__((ext_vector_type(4)));

__device__ __forceinline__ float fsig(float x) {
  return __builtin_amdgcn_rcpf(1.0f + __expf(-x));
}
__device__ __forceinline__ float ftanh(float x) {
  return 2.0f * __builtin_amdgcn_rcpf(1.0f + __expf(-2.0f * x)) - 1.0f;
}

__global__ void prep(const float* __restrict__ Whh, const float* __restrict__ W1,
                     const float* __restrict__ W2, const float* __restrict__ b2,
                     const float* __restrict__ Wf, const float* __restrict__ bf,
                     float* __restrict__ ws) {
  int id = (int)blockIdx.x * 256 + (int)threadIdx.x;
  if (id < 4096) {                       // M' = dt * W1 @ W2
    int j = id >> 6, k = id & 63;
    float s = 0.f;
    for (int l = 0; l < 64; ++l) s += W1[j * 64 + l] * W2[l * 64 + k];
    ws[OFF_M + id] = DT * s;
  } else if (id < 20480) {               // N' = dt * Whh @ W2
    int e = id - 4096; int gr = e >> 6, k = e & 63;
    float s = 0.f;
    for (int l = 0; l < 64; ++l) s += Whh[gr * 64 + l] * W2[l * 64 + k];
    ws[OFF_N + e] = DT * s;
  } else if (id < 24576) {               // P' = dt * Wf @ W2
    int e = id - 20480; int j = e >> 6, k = e & 63;
    float s = 0.f;
    for (int l = 0; l < 64; ++l) s += Wf[j * 64 + l] * W2[l * 64 + k];
    ws[OFF_P + e] = DT * s;
  } else if (id < 24640) {               // k1 = dt * W1 @ b2
    int j = id - 24576;
    float s = 0.f;
    for (int l = 0; l < 64; ++l) s += W1[j * 64 + l] * b2[l];
    ws[OFF_K1 + j] = DT * s;
  } else if (id < 24896) {               // cg = 3dt * Whh @ b2
    int gr = id - 24640;
    float s = 0.f;
    for (int l = 0; l < 64; ++l) s += Whh[gr * 64 + l] * b2[l];
    ws[OFF_CG + gr] = 3.0f * DT * s;
  } else if (id < 24960) {               // c2 = 3dt * Wf @ b2 + bf
    int j = id - 24896;
    float s = 0.f;
    for (int l = 0; l < 64; ++l) s += Wf[j * 64 + l] * b2[l];
    ws[OFF_C2 + j] = 3.0f * DT * s + bf[j];
  }
}

// A-plane: [16 rows][64 cols] fp16, 8-col chunks XOR-swizzled by (row&7).
__device__ __forceinline__ half8 rdA(const _Float16* plane, int off) {
  return *(const half8*)(plane + off);
}

__global__ void __launch_bounds__(256, 2)
odelstm(const float* __restrict__ X, const float* __restrict__ Wih,
        const float* __restrict__ Whh, const float* __restrict__ bih,
        const float* __restrict__ bhh, const float* __restrict__ W1,
        const float* __restrict__ b1, const float* __restrict__ Wf,
        const float* __restrict__ ws, float* __restrict__ OUT)
{
  // planes (1024 halfs each): H0, H1 (ping-pong h_new), T0, T1, Sp
  __shared__ __align__(16) _Float16 sh[5 * 1024];

  const int tid = (int)threadIdx.x;
  const int w = tid >> 6;
  const int l = tid & 63;
  const int q = l >> 4;
  const int p = l & 15;
  const int j = (w << 4) | p;        // owned output column
  const int row0 = (int)blockIdx.x << 3;   // 8 batch rows per block

  // ---- weight B-fragments (fp16) in registers ----
  half8 Bhh[4][2], Bw1[2], Bm[2], Bn[4][2], Bp[2], Bof[2];
  #pragma unroll
  for (int g = 0; g < 4; ++g) {
    #pragma unroll
    for (int kt = 0; kt < 2; ++kt) {
      const float* s  = Whh + ((g << 6) | j) * 64 + (kt << 5) + (q << 3);
      const float* sn = ws + OFF_N + (((g << 6) | j) << 6) + (kt << 5) + (q << 3);
      half8 v, vn;
      #pragma unroll
      for (int i = 0; i < 8; ++i) { v[i] = (_Float16)s[i]; vn[i] = (_Float16)sn[i]; }
      Bhh[g][kt] = v; Bn[g][kt] = vn;
    }
  }
  #pragma unroll
  for (int kt = 0; kt < 2; ++kt) {
    const float* s1 = W1 + j * 64 + (kt << 5) + (q << 3);
    const float* sm = ws + OFF_M + (j << 6) + (kt << 5) + (q << 3);
    const float* sp = ws + OFF_P + (j << 6) + (kt << 5) + (q << 3);
    const float* sf = Wf + j * 64 + (kt << 5) + (q << 3);
    half8 v1, vm, vp, vf;
    #pragma unroll
    for (int i = 0; i < 8; ++i) {
      v1[i] = (_Float16)s1[i]; vm[i] = (_Float16)sm[i];
      vp[i] = (_Float16)sp[i]; vf[i] = (_Float16)sf[i];
    }
    Bw1[kt] = v1; Bm[kt] = vm; Bp[kt] = vp; Bof[kt] = vf;
  }

  // per-lane constants
  float bias0[4], biasL[4], wx0[4], wx1[4];
  #pragma unroll
  for (int g = 0; g < 4; ++g) {
    int gr = (g << 6) | j;
    bias0[g] = bih[gr] + bhh[gr];
    biasL[g] = bias0[g] + ws[OFF_CG + gr];
    wx0[g] = Wih[gr * 2];
    wx1[g] = Wih[gr * 2 + 1];
  }
  const float b1c = b1[j];
  const float k1c = ws[OFF_K1 + j];
  const float c2c = ws[OFF_C2 + j];

  // loop-invariant LDS addresses: valid tile rows are q*4+r, r in {0,1}
  int waddr[2];
  #pragma unroll
  for (int r = 0; r < 2; ++r) {
    int row = (q << 2) | r;
    waddr[r] = row * 64 + (((j >> 3) ^ (row & 7)) << 3) + (j & 7);
  }
  int roff0 = p * 64 + (((q) ^ (p & 7)) << 3);
  int roff1 = p * 64 + (((4 | q) ^ (p & 7)) << 3);

  // global pointers: lane handles batch rows row0 + q*2 + {0,1}
  const float* xp[2];
  float* outp[2];
  #pragma unroll
  for (int r = 0; r < 2; ++r) {
    int rb = row0 + ((q << 1) | r);
    xp[r]   = X + rb * 2 * TT;               // ch0 at [t], ch1 at [TT + t]
    outp[r] = OUT + (rb * TT) * 64 + j;
  }

  // zero all planes once: dead tile rows must stay 0 forever
  for (int i = tid; i < 5 * 1024; i += 256) sh[i] = (_Float16)0.f;

  // prologue: x(0), gates(0) = x Wih + bias (h0 = 0)
  float x0[2], x1[2];
  #pragma unroll
  for (int r = 0; r < 2; ++r) { x0[r] = xp[r][0]; x1[r] = xp[r][TT]; }

  f32x4 acc[4];
  #pragma unroll
  for (int g = 0; g < 4; ++g) {
    acc[g][0] = bias0[g] + x0[0] * wx0[g] + x1[0] * wx1[g];
    acc[g][1] = bias0[g] + x0[1] * wx0[g] + x1[1] * wx1[g];
    acc[g][2] = 0.f; acc[g][3] = 0.f;
  }

  float c[2] = {0.f, 0.f};

  __syncthreads();

  for (int t = 0; t < TT; ++t) {
    _Float16* Hpl = sh + ((t & 1) << 10);       // H0 / H1
    _Float16* T0p = sh + 2048;
    _Float16* T1p = sh + 3072;
    _Float16* Spp = sh + 4096;

    // ---- phase 1: LSTM pointwise -> h_new; write H plane ----
    #pragma unroll
    for (int r = 0; r < 2; ++r) {
      float ig = fsig(acc[0][r]);
      float fg = fsig(acc[1][r]);
      float gg = ftanh(acc[2][r]);
      float og = fsig(acc[3][r]);
      c[r] = fg * c[r] + ig * gg;
      float hv = og * ftanh(c[r]);
      Hpl[waddr[r]] = (_Float16)hv;
    }
    __syncthreads();  // b1

    // ---- phase 2: a0 = W1 h_new + b1 ; prefetch x(t+1) ----
    half8 hf0 = rdA(Hpl, roff0);
    half8 hf1 = rdA(Hpl, roff1);
    f32x4 aa = {b1c, b1c, b1c, b1c};
    aa = __builtin_amdgcn_mfma_f32_16x16x32_f16(hf0, Bw1[0], aa, 0, 0, 0);
    aa = __builtin_amdgcn_mfma_f32_16x16x32_f16(hf1, Bw1[1], aa, 0, 0, 0);

    int tn = (t + 1 < TT) ? t + 1 : t;
    float nx0[2], nx1[2];
    #pragma unroll
    for (int r = 0; r < 2; ++r) { nx0[r] = xp[r][tn]; nx1[r] = xp[r][TT + tn]; }

    // ---- phase 3: t0 = tanh(a0); a1 = a0 + M' t0 + k1 ----
    float t0s[2];
    #pragma unroll
    for (int r = 0; r < 2; ++r) {
      t0s[r] = ftanh(aa[r]);
      T0p[waddr[r]] = (_Float16)t0s[r];
    }
    __syncthreads();  // b2
    half8 t0f0 = rdA(T0p, roff0);
    half8 t0f1 = rdA(T0p, roff1);
    f32x4 a1 = {aa[0] + k1c, aa[1] + k1c, 0.f, 0.f};
    a1 = __builtin_amdgcn_mfma_f32_16x16x32_f16(t0f0, Bm[0], a1, 0, 0, 0);
    a1 = __builtin_amdgcn_mfma_f32_16x16x32_f16(t0f1, Bm[1], a1, 0, 0, 0);

    // ---- phase 4: t1 = tanh(a1); a2 = a1 + M' t1 + k1 ----
    float t1s[2];
    #pragma unroll
    for (int r = 0; r < 2; ++r) {
      t1s[r] = ftanh(a1[r]);
      T1p[waddr[r]] = (_Float16)t1s[r];
    }
    __syncthreads();  // b3
    half8 t1f0 = rdA(T1p, roff0);
    half8 t1f1 = rdA(T1p, roff1);
    f32x4 a2 = {a1[0] + k1c, a1[1] + k1c, 0.f, 0.f};
    a2 = __builtin_amdgcn_mfma_f32_16x16x32_f16(t1f0, Bm[0], a2, 0, 0, 0);
    a2 = __builtin_amdgcn_mfma_f32_16x16x32_f16(t1f1, Bm[1], a2, 0, 0, 0);

    // ---- phase 5: t2 = tanh(a2); S = t0+t1+t2; write Sp ----
    #pragma unroll
    for (int r = 0; r < 2; ++r) {
      float Sv = t0s[r] + t1s[r] + ftanh(a2[r]);
      Spp[waddr[r]] = (_Float16)Sv;
    }
    __syncthreads();  // b4

    // ---- phase 6: gates(t+1) = x Wih + biasL + Whh H + N' S ;
    //               out_t = Wf H + P' S + c2 ----
    half8 sf0 = rdA(Spp, roff0);
    half8 sf1 = rdA(Spp, roff1);

    #pragma unroll
    for (int g = 0; g < 4; ++g) {
      acc[g][0] = biasL[g] + nx0[0] * wx0[g] + nx1[0] * wx1[g];
      acc[g][1] = biasL[g] + nx0[1] * wx0[g] + nx1[1] * wx1[g];
      acc[g][2] = 0.f; acc[g][3] = 0.f;
      acc[g] = __builtin_amdgcn_mfma_f32_16x16x32_f16(hf0, Bhh[g][0], acc[g], 0, 0, 0);
      acc[g] = __builtin_amdgcn_mfma_f32_16x16x32_f16(hf1, Bhh[g][1], acc[g], 0, 0, 0);
      acc[g] = __builtin_amdgcn_mfma_f32_16x16x32_f16(sf0, Bn[g][0],  acc[g], 0, 0, 0);
      acc[g] = __builtin_amdgcn_mfma_f32_16x16x32_f16(sf1, Bn[g][1],  acc[g], 0, 0, 0);
    }

    f32x4 oa = {c2c, c2c, 0.f, 0.f};
    oa = __builtin_amdgcn_mfma_f32_16x16x32_f16(hf0, Bof[0], oa, 0, 0, 0);
    oa = __builtin_amdgcn_mfma_f32_16x16x32_f16(hf1, Bof[1], oa, 0, 0, 0);
    oa = __builtin_amdgcn_mfma_f32_16x16x32_f16(sf0, Bp[0],  oa, 0, 0, 0);
    oa = __builtin_amdgcn_mfma_f32_16x16x32_f16(sf1, Bp[1],  oa, 0, 0, 0);

    #pragma unroll
    for (int r = 0; r < 2; ++r) {
      outp[r][0] = oa[r];
      outp[r] += 64;
    }

    #pragma unroll
    for (int r = 0; r < 2; ++r) { x0[r] = nx0[r]; x1[r] = nx1[r]; }
  }
}

extern "C" void kernel_launch(void* const* d_in, const int* in_sizes, int n_in,
                              void* d_out, int out_size, void* d_ws, size_t ws_size,
                              hipStream_t stream) {
  const float* X   = (const float*)d_in[0];
  const float* Wih = (const float*)d_in[1];
  const float* Whh = (const float*)d_in[2];
  const float* bih = (const float*)d_in[3];
  const float* bhh = (const float*)d_in[4];
  const float* W1  = (const float*)d_in[5];
  const float* b1  = (const float*)d_in[6];
  const float* W2  = (const float*)d_in[7];
  const float* b2  = (const float*)d_in[8];
  const float* Wf  = (const float*)d_in[9];
  const float* bf  = (const float*)d_in[10];
  float* OUT = (float*)d_out;
  float* ws  = (float*)d_ws;

  hipLaunchKernelGGL(prep, dim3(98), dim3(256), 0, stream,
                     Whh, W1, W2, b2, Wf, bf, ws);

  int B = in_sizes[0] / (2 * TT);   // 4096
  dim3 grid(B / 8), block(256);     // 512 blocks -> 2 blocks/CU
  hipLaunchKernelGGL(odelstm, grid, block, 0, stream,
                     X, Wih, Whh, bih, bhh, W1, b1, Wf, ws, OUT);
}